// Round 1
// baseline (4762.070 us; speedup 1.0000x reference)
//
#include <hip/hip_runtime.h>
#include <hip/hip_bf16.h>

#define BB   8
#define HGT  128
#define WID  128
#define CC   192
#define LLEN (HGT*WID)        // 16384
#define MM   (BB*LLEN)        // 131072
#define NF   388              // 2C + FL + 1
#define HIDN 768

typedef unsigned short us16;

__device__ __forceinline__ float bf2f(us16 u) {
    return __uint_as_float(((unsigned int)u) << 16);
}
__device__ __forceinline__ us16 f2bf(float f) {
    unsigned int x = __float_as_uint(f);
    x = (x + 0x7fffu + ((x >> 16) & 1u)) >> 16;
    return (us16)x;
}
__device__ __forceinline__ float gelu_f(float x) {
    return 0.5f * x * (1.0f + erff(x * 0.70710678118654752f));
}

// ---------------- LayerNorm: fp32 in -> bf16 out (wave per row) ----------------
__global__ __launch_bounds__(256) void ln_kernel(const float* __restrict__ in,
                                                 const float* __restrict__ g,
                                                 const float* __restrict__ b,
                                                 us16* __restrict__ out) {
    int wid  = threadIdx.x >> 6;
    int lane = threadIdx.x & 63;
    int row  = blockIdx.x * 4 + wid;
    const float* p = in + (size_t)row * CC;
    float v0 = p[lane], v1 = p[lane + 64], v2 = p[lane + 128];
    float s1 = v0 + v1 + v2;
    float s2 = v0*v0 + v1*v1 + v2*v2;
    for (int o = 32; o; o >>= 1) { s1 += __shfl_xor(s1, o); s2 += __shfl_xor(s2, o); }
    float m   = s1 * (1.0f / 192.0f);
    float var = s2 * (1.0f / 192.0f) - m * m;
    float inv = rsqrtf(var + 1e-5f);
    us16* q = out + (size_t)row * CC;
    q[lane]       = f2bf((v0 - m) * inv * g[lane]       + b[lane]);
    q[lane + 64]  = f2bf((v1 - m) * inv * g[lane + 64]  + b[lane + 64]);
    q[lane + 128] = f2bf((v2 - m) * inv * g[lane + 128] + b[lane + 128]);
}

// ---------------- Tiled GEMM: A(bf16 M x 192) * B(f32) -----------------------
// MODE 0: B = f_w (192 x 388) + f_b, scatter -> q / ctx / gates
// MODE 1: B = h_w^T (acc = ctx_all @ h_w^T) + h_b + g3*hg, * q -> xq (bf16)
// MODE 2: B = proj_w (192 x 192) + proj_b + shortcut x -> d_out (f32)
template<int MODE>
__global__ __launch_bounds__(256) void gemm_kernel(const us16* __restrict__ A,
                            const float* __restrict__ Bw,
                            const float* __restrict__ bias,
                            us16* __restrict__ out_q,
                            us16* __restrict__ out_ctx,
                            us16* __restrict__ out_gates,
                            const us16* __restrict__ q_in,
                            const us16* __restrict__ gates_in,
                            const float* __restrict__ hg,
                            const float* __restrict__ x_in,
                            float* __restrict__ out_f) {
    constexpr int N = (MODE == 0) ? NF : CC;
    constexpr int K = CC;
    __shared__ float As[16][68];
    __shared__ float Bs[16][68];
    int tid = threadIdx.x;
    int m0 = blockIdx.x * 64;
    int n0 = blockIdx.y * 64;
    int tx = tid & 15, ty = tid >> 4;
    int am = tid >> 2, ak = (tid & 3) * 4;
    float acc[4][4] = {};
    for (int k0 = 0; k0 < K; k0 += 16) {
        const us16* ap = A + (size_t)(m0 + am) * K + k0 + ak;
        uint2 av = *reinterpret_cast<const uint2*>(ap);
        As[ak + 0][am] = bf2f((us16)(av.x & 0xffffu));
        As[ak + 1][am] = bf2f((us16)(av.x >> 16));
        As[ak + 2][am] = bf2f((us16)(av.y & 0xffffu));
        As[ak + 3][am] = bf2f((us16)(av.y >> 16));
        if (MODE == 1) {
            int bn = tid >> 2, bk = (tid & 3) * 4;
            const float* bp = Bw + (size_t)(n0 + bn) * K + k0 + bk;
            float4 bv = *reinterpret_cast<const float4*>(bp);
            Bs[bk + 0][bn] = bv.x; Bs[bk + 1][bn] = bv.y;
            Bs[bk + 2][bn] = bv.z; Bs[bk + 3][bn] = bv.w;
        } else {
            int bk = tid >> 4, bn4 = (tid & 15) * 4;
            int n = n0 + bn4;
            const float* bp = Bw + (size_t)(k0 + bk) * N + n;
            if (MODE == 0 && n + 4 > N) {
                for (int i2 = 0; i2 < 4; i2++)
                    Bs[bk][bn4 + i2] = (n + i2 < N) ? bp[i2] : 0.0f;
            } else {
                float4 bv = *reinterpret_cast<const float4*>(bp);
                Bs[bk][bn4 + 0] = bv.x; Bs[bk][bn4 + 1] = bv.y;
                Bs[bk][bn4 + 2] = bv.z; Bs[bk][bn4 + 3] = bv.w;
            }
        }
        __syncthreads();
        #pragma unroll
        for (int k = 0; k < 16; k++) {
            float4 a = *reinterpret_cast<const float4*>(&As[k][ty * 4]);
            float4 bv = *reinterpret_cast<const float4*>(&Bs[k][tx * 4]);
            float ar[4] = {a.x, a.y, a.z, a.w};
            float br[4] = {bv.x, bv.y, bv.z, bv.w};
            #pragma unroll
            for (int i = 0; i < 4; i++)
                #pragma unroll
                for (int j = 0; j < 4; j++)
                    acc[i][j] += ar[i] * br[j];
        }
        __syncthreads();
    }
    #pragma unroll
    for (int i = 0; i < 4; i++) {
        int r = m0 + ty * 4 + i;
        if (MODE == 0) {
            #pragma unroll
            for (int j = 0; j < 4; j++) {
                int cc = n0 + tx * 4 + j;
                if (cc < NF) {
                    float val = acc[i][j] + bias[cc];
                    if (cc < CC)          out_q[(size_t)r * CC + cc]            = f2bf(val);
                    else if (cc < 2 * CC) out_ctx[(size_t)r * CC + (cc - CC)]   = f2bf(val);
                    else                  out_gates[(size_t)r * 4 + (cc - 2*CC)] = f2bf(val);
                }
            }
        } else if (MODE == 1) {
            int bidx = m0 >> 14;
            float g3 = bf2f(gates_in[(size_t)r * 4 + 3]);
            #pragma unroll
            for (int j = 0; j < 4; j++) {
                int cc = n0 + tx * 4 + j;
                float val = acc[i][j] + bias[cc] + g3 * hg[bidx * CC + cc];
                val *= bf2f(q_in[(size_t)r * CC + cc]);
                out_q[(size_t)r * CC + cc] = f2bf(val);
            }
        } else {
            #pragma unroll
            for (int j = 0; j < 4; j++) {
                int cc = n0 + tx * 4 + j;
                float val = acc[i][j] + bias[cc] + x_in[(size_t)r * CC + cc];
                out_f[(size_t)r * CC + cc] = val;
            }
        }
    }
}

// ---------------- Depthwise conv (NHWC) + gelu + gated ctx_all accumulation ----
template<int F, bool FIRST>
__global__ __launch_bounds__(256) void conv_kernel(const us16* __restrict__ in,
                            us16* __restrict__ outp,
                            us16* __restrict__ ctx_all,
                            const us16* __restrict__ gates,
                            const float* __restrict__ kw, int lvl) {
    __shared__ float kws[CC * F * F];
    for (int t = threadIdx.x; t < CC * F * F; t += 256) kws[t] = kw[t];
    __syncthreads();
    int idx  = blockIdx.x * 256 + threadIdx.x;
    int c    = idx % CC;
    int rest = idx / CC;            // b*16384 + y*128 + x
    int x0 = rest & 127;
    int y0 = (rest >> 7) & 127;
    int b  = rest >> 14;
    constexpr int P = F / 2;
    float acc = 0.0f;
    #pragma unroll
    for (int i = 0; i < F; i++) {
        int yy = y0 + i - P;
        if (yy < 0 || yy > 127) continue;
        #pragma unroll
        for (int j = 0; j < F; j++) {
            int xx = x0 + j - P;
            if (xx < 0 || xx > 127) continue;
            acc += bf2f(in[(((size_t)(b * 128 + yy)) * 128 + xx) * CC + c]) * kws[c * F * F + i * F + j];
        }
    }
    float val = gelu_f(acc);
    outp[idx] = f2bf(val);
    float gl = bf2f(gates[(size_t)rest * 4 + lvl]);
    float contrib = val * gl;
    if (FIRST) ctx_all[idx] = f2bf(contrib);
    else       ctx_all[idx] = f2bf(bf2f(ctx_all[idx]) + contrib);
}

// ---------------- Global mean stage 1: per (b, hw-chunk) partial sums ----------
__global__ __launch_bounds__(192) void gmean1_kernel(const us16* __restrict__ ctx,
                                                     float* __restrict__ partial) {
    int blk = blockIdx.x;           // 0..1023
    int b = blk >> 7, chunk = blk & 127;
    int c = threadIdx.x;
    size_t base = ((size_t)b * LLEN + (size_t)chunk * 128) * CC + c;
    float s = 0.0f;
    for (int p = 0; p < 128; p++) s += bf2f(ctx[base + (size_t)p * CC]);
    partial[(size_t)blk * CC + c] = s;
}

// ---------------- Global mean stage 2 + hg = h_w @ gelu(mean) ------------------
__global__ __launch_bounds__(256) void gmean2_kernel(const float* __restrict__ partial,
                                                     const float* __restrict__ h_w,
                                                     float* __restrict__ hg) {
    __shared__ float ctxg[BB * CC];
    for (int t = threadIdx.x; t < BB * CC; t += 256) {
        int b = t / CC, c = t % CC;
        float s = 0.0f;
        for (int p = 0; p < 128; p++) s += partial[(size_t)(b * 128 + p) * CC + c];
        ctxg[t] = gelu_f(s * (1.0f / 16384.0f));
    }
    __syncthreads();
    for (int t = threadIdx.x; t < BB * CC; t += 256) {
        int b = t / CC, o = t % CC;
        float s = 0.0f;
        for (int c2 = 0; c2 < CC; c2++) s += h_w[o * CC + c2] * ctxg[b * CC + c2];
        hg[t] = s;
    }
}

// ---------------- Fused MLP: 16 rows/block, fc1+gelu in LDS, fc2 + residual ----
__global__ __launch_bounds__(256) void mlp_kernel(const us16* __restrict__ ln2t,
                           const float* __restrict__ fc1_w, const float* __restrict__ fc1_b,
                           const float* __restrict__ fc2_w, const float* __restrict__ fc2_b,
                           float* __restrict__ io) {
    __shared__ float xin[16][CC];
    __shared__ float hid[16][HIDN];
    int tid  = threadIdx.x;
    int row0 = blockIdx.x * 16;
    for (int t = tid; t < 16 * CC; t += 256) {
        int r = t / CC, c = t % CC;
        xin[r][c] = bf2f(ln2t[(size_t)(row0 + r) * CC + c]);
    }
    __syncthreads();
    {   // phase 1: hid = gelu(xin @ fc1_w + fc1_b)
        int half = tid >> 7;
        int jj   = tid & 127;
        int r0   = half * 8;
        for (int js = 0; js < 3; js++) {
            int j = js * 256 + jj * 2;
            float acc0[8], acc1[8];
            float b0 = fc1_b[j], b1 = fc1_b[j + 1];
            #pragma unroll
            for (int r = 0; r < 8; r++) { acc0[r] = b0; acc1[r] = b1; }
            for (int k = 0; k < CC; k += 4) {
                float2 w0 = *reinterpret_cast<const float2*>(&fc1_w[(size_t)(k + 0) * HIDN + j]);
                float2 w1 = *reinterpret_cast<const float2*>(&fc1_w[(size_t)(k + 1) * HIDN + j]);
                float2 w2 = *reinterpret_cast<const float2*>(&fc1_w[(size_t)(k + 2) * HIDN + j]);
                float2 w3 = *reinterpret_cast<const float2*>(&fc1_w[(size_t)(k + 3) * HIDN + j]);
                #pragma unroll
                for (int r = 0; r < 8; r++) {
                    float4 xv = *reinterpret_cast<const float4*>(&xin[r0 + r][k]);
                    acc0[r] += xv.x * w0.x + xv.y * w1.x + xv.z * w2.x + xv.w * w3.x;
                    acc1[r] += xv.x * w0.y + xv.y * w1.y + xv.z * w2.y + xv.w * w3.y;
                }
            }
            #pragma unroll
            for (int r = 0; r < 8; r++) {
                hid[r0 + r][j]     = gelu_f(acc0[r]);
                hid[r0 + r][j + 1] = gelu_f(acc1[r]);
            }
        }
    }
    __syncthreads();
    if (tid < 192) {  // phase 2: y = hid @ fc2_w + fc2_b ; io += y
        int half = tid / 96;
        int cp   = tid % 96;
        int r0   = half * 8;
        int c0 = cp, c1 = cp + 96;
        float a0[8], a1[8];
        float b0 = fc2_b[c0], b1 = fc2_b[c1];
        #pragma unroll
        for (int r = 0; r < 8; r++) { a0[r] = b0; a1[r] = b1; }
        for (int j = 0; j < HIDN; j += 4) {
            float w00 = fc2_w[(size_t)(j + 0) * CC + c0], w01 = fc2_w[(size_t)(j + 0) * CC + c1];
            float w10 = fc2_w[(size_t)(j + 1) * CC + c0], w11 = fc2_w[(size_t)(j + 1) * CC + c1];
            float w20 = fc2_w[(size_t)(j + 2) * CC + c0], w21 = fc2_w[(size_t)(j + 2) * CC + c1];
            float w30 = fc2_w[(size_t)(j + 3) * CC + c0], w31 = fc2_w[(size_t)(j + 3) * CC + c1];
            #pragma unroll
            for (int r = 0; r < 8; r++) {
                float4 hv = *reinterpret_cast<const float4*>(&hid[r0 + r][j]);
                a0[r] += hv.x * w00 + hv.y * w10 + hv.z * w20 + hv.w * w30;
                a1[r] += hv.x * w01 + hv.y * w11 + hv.z * w21 + hv.w * w31;
            }
        }
        #pragma unroll
        for (int r = 0; r < 8; r++) {
            size_t o = (size_t)(row0 + r0 + r) * CC;
            io[o + c0] += a0[r];
            io[o + c1] += a1[r];
        }
    }
}

extern "C" void kernel_launch(void* const* d_in, const int* in_sizes, int n_in,
                              void* d_out, int out_size, void* d_ws, size_t ws_size,
                              hipStream_t stream) {
    const float* x      = (const float*)d_in[0];
    const float* ln1_g  = (const float*)d_in[1];
    const float* ln1_b  = (const float*)d_in[2];
    const float* f_w    = (const float*)d_in[3];
    const float* f_b    = (const float*)d_in[4];
    const float* fk0    = (const float*)d_in[5];
    const float* fk1    = (const float*)d_in[6];
    const float* fk2    = (const float*)d_in[7];
    const float* h_w    = (const float*)d_in[8];
    const float* h_b    = (const float*)d_in[9];
    const float* proj_w = (const float*)d_in[10];
    const float* proj_b = (const float*)d_in[11];
    const float* ln2_g  = (const float*)d_in[12];
    const float* ln2_b  = (const float*)d_in[13];
    const float* fc1_w  = (const float*)d_in[14];
    const float* fc1_b  = (const float*)d_in[15];
    const float* fc2_w  = (const float*)d_in[16];
    const float* fc2_b  = (const float*)d_in[17];
    float* outp = (float*)d_out;

    char* ws = (char*)d_ws;
    const size_t S = (size_t)MM * CC * 2;          // 50,331,648 B (one bf16 plane)
    us16* t_buf   = (us16*)(ws);                   // t / xq (reused)
    us16* q_buf   = (us16*)(ws + S);
    us16* ctx_all = (us16*)(ws + 2 * S);
    us16* gates   = (us16*)(ws + 3 * S);
    float* partial = (float*)(ws + 3 * S + (size_t)MM * 4 * 2);
    float* hg      = partial + 1024 * CC;
    // conv ping-pong lives in d_out (dead until proj rewrites it fully)
    us16* ctxA = (us16*)d_out;
    us16* ctxB = (us16*)d_out + (size_t)MM * CC;

    ln_kernel<<<MM / 4, 256, 0, stream>>>(x, ln1_g, ln1_b, t_buf);

    gemm_kernel<0><<<dim3(MM / 64, 7), 256, 0, stream>>>(
        t_buf, f_w, f_b, q_buf, ctxA, gates, nullptr, nullptr, nullptr, nullptr, nullptr);

    const int convGrid = (MM * CC) / 256;
    conv_kernel<3, true ><<<convGrid, 256, 0, stream>>>(ctxA, ctxB, ctx_all, gates, fk0, 0);
    conv_kernel<5, false><<<convGrid, 256, 0, stream>>>(ctxB, ctxA, ctx_all, gates, fk1, 1);
    conv_kernel<7, false><<<convGrid, 256, 0, stream>>>(ctxA, ctxB, ctx_all, gates, fk2, 2);

    gmean1_kernel<<<1024, 192, 0, stream>>>(ctxB, partial);
    gmean2_kernel<<<1, 256, 0, stream>>>(partial, h_w, hg);

    gemm_kernel<1><<<dim3(MM / 64, 3), 256, 0, stream>>>(
        ctx_all, h_w, h_b, t_buf, nullptr, nullptr, q_buf, gates, hg, nullptr, nullptr);

    gemm_kernel<2><<<dim3(MM / 64, 3), 256, 0, stream>>>(
        t_buf, proj_w, proj_b, nullptr, nullptr, nullptr, nullptr, nullptr, nullptr, x, outp);

    ln_kernel<<<MM / 4, 256, 0, stream>>>(outp, ln2_g, ln2_b, t_buf);

    mlp_kernel<<<MM / 16, 256, 0, stream>>>(t_buf, fc1_w, fc1_b, fc2_w, fc2_b, outp);
}

// Round 2
// 2914.304 us; speedup vs baseline: 1.6340x; 1.6340x over previous
//
#include <hip/hip_runtime.h>
#include <hip/hip_bf16.h>

#define BB   8
#define HGT  128
#define WID  128
#define CC   192
#define LLEN (HGT*WID)        // 16384
#define MM   (BB*LLEN)        // 131072
#define NF   388              // 2C + FL + 1
#define HIDN 768

typedef unsigned short us16;
typedef __attribute__((ext_vector_type(8))) short bf16x8;
typedef __attribute__((ext_vector_type(4))) float f32x4;

__device__ __forceinline__ float bf2f(us16 u) {
    return __uint_as_float(((unsigned int)u) << 16);
}
__device__ __forceinline__ us16 f2bf(float f) {
    unsigned int x = __float_as_uint(f);
    x = (x + 0x7fffu + ((x >> 16) & 1u)) >> 16;
    return (us16)x;
}
__device__ __forceinline__ float gelu_f(float x) {
    return 0.5f * x * (1.0f + erff(x * 0.70710678118654752f));
}

// ---------------- Weight convert: fp32 -> bf16, transposed to [N][K] ----------
__global__ __launch_bounds__(256) void wcvt_kernel(const float* __restrict__ f_w,
        const float* __restrict__ h_w, const float* __restrict__ proj_w,
        const float* __restrict__ fc1_w, const float* __restrict__ fc2_w,
        us16* __restrict__ fwT, us16* __restrict__ hwB, us16* __restrict__ projT,
        us16* __restrict__ w1T, us16* __restrict__ w2T) {
    int i = blockIdx.x * 256 + threadIdx.x;
    if (i < 86016) {                       // fwT: 448 x 192 (pad rows >= 388 = 0)
        int n = i / 192, k = i % 192;
        fwT[i] = (n < NF) ? f2bf(f_w[k * NF + n]) : (us16)0;
        return;
    }
    i -= 86016;
    if (i < 36864) { hwB[i] = f2bf(h_w[i]); return; }       // h_w[o][c] is already [N][K]
    i -= 36864;
    if (i < 36864) { int n = i / 192, k = i % 192; projT[i] = f2bf(proj_w[k * CC + n]); return; }
    i -= 36864;
    if (i < 147456) { int n = i / 192, k = i % 192; w1T[i] = f2bf(fc1_w[k * HIDN + n]); return; }
    i -= 147456;
    if (i < 147456) { int n = i / 768, k = i % 768; w2T[i] = f2bf(fc2_w[k * CC + n]); return; }
}

// ---------------- LayerNorm: fp32 in -> bf16 out (wave per row) ----------------
__global__ __launch_bounds__(256) void ln_kernel(const float* __restrict__ in,
                                                 const float* __restrict__ g,
                                                 const float* __restrict__ b,
                                                 us16* __restrict__ out) {
    int wid  = threadIdx.x >> 6;
    int lane = threadIdx.x & 63;
    int row  = blockIdx.x * 4 + wid;
    const float* p = in + (size_t)row * CC;
    float v0 = p[lane], v1 = p[lane + 64], v2 = p[lane + 128];
    float s1 = v0 + v1 + v2;
    float s2 = v0*v0 + v1*v1 + v2*v2;
    for (int o = 32; o; o >>= 1) { s1 += __shfl_xor(s1, o); s2 += __shfl_xor(s2, o); }
    float m   = s1 * (1.0f / 192.0f);
    float var = s2 * (1.0f / 192.0f) - m * m;
    float inv = rsqrtf(var + 1e-5f);
    us16* q = out + (size_t)row * CC;
    q[lane]       = f2bf((v0 - m) * inv * g[lane]       + b[lane]);
    q[lane + 64]  = f2bf((v1 - m) * inv * g[lane + 64]  + b[lane + 64]);
    q[lane + 128] = f2bf((v2 - m) * inv * g[lane + 128] + b[lane + 128]);
}

// ---------------- MFMA GEMM: A(bf16 MxK=192) * Bt(bf16 [N][K]) ---------------
// Fragments loaded directly from global (L1/L2-cached); no LDS, no barriers.
// MODE 0: Bt=fwT (448x192), +f_b, scatter -> q / ctx / gates
// MODE 1: Bt=h_w  (modulator), +h_b + g3*hg, * q -> bf16 out
// MODE 2: Bt=projT, +proj_b + shortcut x -> f32 out
template<int MODE>
__global__ __launch_bounds__(256) void mgemm_kernel(const us16* __restrict__ A,
        const us16* __restrict__ Bt, const float* __restrict__ bias,
        us16* __restrict__ out_q, us16* __restrict__ out_ctx, us16* __restrict__ out_g,
        const us16* __restrict__ q_in, const us16* __restrict__ gates_in,
        const float* __restrict__ hg, const float* __restrict__ x_in,
        float* __restrict__ out_f) {
    constexpr int NT = (MODE == 0) ? 7 : 3;
    int id  = blockIdx.x;
    int xcd = id & 7;
    int s   = id >> 3;
    int mt  = xcd * 128 + s / NT;          // all N-tiles of an M-tile on one XCD
    int nt  = s % NT;
    int m0 = mt * 128, n0 = nt * 64;
    int tid = threadIdx.x, lane = tid & 63, w = tid >> 6;
    int wm = w >> 1, wn = w & 1, g = lane >> 4, lr = lane & 15;
    const us16* Ab = A  + (size_t)(m0 + wm * 64 + lr) * CC;
    const us16* Bb = Bt + (size_t)(n0 + wn * 32 + lr) * CC;
    f32x4 acc[4][2] = {};
    #pragma unroll
    for (int kk = 0; kk < 6; kk++) {
        int k = kk * 32 + g * 8;
        bf16x8 a0 = *(const bf16x8*)(Ab + 0 * 16 * CC + k);
        bf16x8 a1 = *(const bf16x8*)(Ab + 1 * 16 * CC + k);
        bf16x8 a2 = *(const bf16x8*)(Ab + 2 * 16 * CC + k);
        bf16x8 a3 = *(const bf16x8*)(Ab + 3 * 16 * CC + k);
        #pragma unroll
        for (int j = 0; j < 2; j++) {
            bf16x8 bv = *(const bf16x8*)(Bb + (size_t)j * 16 * CC + k);
            acc[0][j] = __builtin_amdgcn_mfma_f32_16x16x32_bf16(a0, bv, acc[0][j], 0, 0, 0);
            acc[1][j] = __builtin_amdgcn_mfma_f32_16x16x32_bf16(a1, bv, acc[1][j], 0, 0, 0);
            acc[2][j] = __builtin_amdgcn_mfma_f32_16x16x32_bf16(a2, bv, acc[2][j], 0, 0, 0);
            acc[3][j] = __builtin_amdgcn_mfma_f32_16x16x32_bf16(a3, bv, acc[3][j], 0, 0, 0);
        }
    }
    int orow = m0 + wm * 64;
    #pragma unroll
    for (int i = 0; i < 4; i++) {
        #pragma unroll
        for (int j = 0; j < 2; j++) {
            int ncol = n0 + wn * 32 + j * 16;
            int cc   = ncol + lr;
            #pragma unroll
            for (int r = 0; r < 4; r++) {
                int row = orow + i * 16 + g * 4 + r;
                float v = acc[i][j][r];
                if (MODE == 0) {
                    if (ncol < 192)      out_q[(size_t)row * CC + cc]          = f2bf(v + bias[cc]);
                    else if (ncol < 384) out_ctx[(size_t)row * CC + (cc - 192)] = f2bf(v + bias[cc]);
                    else if (cc < NF)    out_g[(size_t)row * 4 + (cc - 384)]    = f2bf(v + bias[cc]);
                } else if (MODE == 1) {
                    int bidx = row >> 14;
                    float val = v + bias[cc] + bf2f(gates_in[(size_t)row * 4 + 3]) * hg[bidx * CC + cc];
                    val *= bf2f(q_in[(size_t)row * CC + cc]);
                    out_q[(size_t)row * CC + cc] = f2bf(val);
                } else {
                    out_f[(size_t)row * CC + cc] = v + bias[cc] + x_in[(size_t)row * CC + cc];
                }
            }
        }
    }
}

// ---------------- Depthwise conv (NHWC) + gelu + gated ctx_all accumulation ----
template<int F, bool FIRST>
__global__ __launch_bounds__(256) void conv_kernel(const us16* __restrict__ in,
                            us16* __restrict__ outp,
                            us16* __restrict__ ctx_all,
                            const us16* __restrict__ gates,
                            const float* __restrict__ kw, int lvl) {
    __shared__ float kws[CC * F * F];
    for (int t = threadIdx.x; t < CC * F * F; t += 256) kws[t] = kw[t];
    __syncthreads();
    int idx  = blockIdx.x * 256 + threadIdx.x;
    int c    = idx % CC;
    int rest = idx / CC;            // b*16384 + y*128 + x
    int x0 = rest & 127;
    int y0 = (rest >> 7) & 127;
    int b  = rest >> 14;
    constexpr int P = F / 2;
    float acc = 0.0f;
    #pragma unroll
    for (int i = 0; i < F; i++) {
        int yy = y0 + i - P;
        if (yy < 0 || yy > 127) continue;
        #pragma unroll
        for (int j = 0; j < F; j++) {
            int xx = x0 + j - P;
            if (xx < 0 || xx > 127) continue;
            acc += bf2f(in[(((size_t)(b * 128 + yy)) * 128 + xx) * CC + c]) * kws[c * F * F + i * F + j];
        }
    }
    float val = gelu_f(acc);
    outp[idx] = f2bf(val);
    float gl = bf2f(gates[(size_t)rest * 4 + lvl]);
    float contrib = val * gl;
    if (FIRST) ctx_all[idx] = f2bf(contrib);
    else       ctx_all[idx] = f2bf(bf2f(ctx_all[idx]) + contrib);
}

// ---------------- Global mean stage 1 ----------
__global__ __launch_bounds__(192) void gmean1_kernel(const us16* __restrict__ ctx,
                                                     float* __restrict__ partial) {
    int blk = blockIdx.x;           // 0..1023
    int b = blk >> 7, chunk = blk & 127;
    int c = threadIdx.x;
    size_t base = ((size_t)b * LLEN + (size_t)chunk * 128) * CC + c;
    float s = 0.0f;
    for (int p = 0; p < 128; p++) s += bf2f(ctx[base + (size_t)p * CC]);
    partial[(size_t)blk * CC + c] = s;
}

// ---------------- Global mean stage 2 + hg = h_w @ gelu(mean) ------------------
__global__ __launch_bounds__(256) void gmean2_kernel(const float* __restrict__ partial,
                                                     const float* __restrict__ h_w,
                                                     float* __restrict__ hg) {
    __shared__ float ctxg[BB * CC];
    for (int t = threadIdx.x; t < BB * CC; t += 256) {
        int b = t / CC, c = t % CC;
        float s = 0.0f;
        for (int p = 0; p < 128; p++) s += partial[(size_t)(b * 128 + p) * CC + c];
        ctxg[t] = gelu_f(s * (1.0f / 16384.0f));
    }
    __syncthreads();
    for (int t = threadIdx.x; t < BB * CC; t += 256) {
        int b = t / CC, o = t % CC;
        float s = 0.0f;
        for (int c2 = 0; c2 < CC; c2++) s += h_w[o * CC + c2] * ctxg[b * CC + c2];
        hg[t] = s;
    }
}

// ---------------- Fused LN2 + MLP (MFMA), in-place on d_out --------------------
// 32 rows/block, 8 waves. xb/hid LDS XOR-swizzled: byte ^= (row&7)<<4 (G4 fix).
#define MB 32
__global__ __launch_bounds__(512) void mlpf_kernel(const float* __restrict__ x1,
        const float* __restrict__ ln2_g, const float* __restrict__ ln2_b,
        const us16* __restrict__ w1T, const float* __restrict__ fc1_b,
        const us16* __restrict__ w2T, const float* __restrict__ fc2_b,
        float* __restrict__ outp) {
    __shared__ us16 xb[MB * CC];       // 12 KB, swizzled
    __shared__ us16 hid[MB * HIDN];    // 48 KB, swizzled
    int tid = threadIdx.x, lane = tid & 63, w = tid >> 6;
    int g = lane >> 4, lr = lane & 15;
    int m0 = blockIdx.x * MB;
    // ---- LN2 phase: wave w handles rows w*4 .. w*4+3 ----
    #pragma unroll
    for (int rr = 0; rr < 4; rr++) {
        int rb = w * 4 + rr;
        const float* p = x1 + (size_t)(m0 + rb) * CC;
        float v0 = p[lane], v1 = p[lane + 64], v2 = p[lane + 128];
        float s1 = v0 + v1 + v2, s2 = v0*v0 + v1*v1 + v2*v2;
        for (int o = 32; o; o >>= 1) { s1 += __shfl_xor(s1, o); s2 += __shfl_xor(s2, o); }
        float m   = s1 * (1.0f / 192.0f);
        float inv = rsqrtf(s2 * (1.0f / 192.0f) - m * m + 1e-5f);
        int sw = (rb & 7) << 4;
        char* base = (char*)xb;
        *(us16*)(base + ((rb * 384 + lane * 2)         ^ sw)) = f2bf((v0 - m) * inv * ln2_g[lane]       + ln2_b[lane]);
        *(us16*)(base + ((rb * 384 + (lane + 64) * 2)  ^ sw)) = f2bf((v1 - m) * inv * ln2_g[lane + 64]  + ln2_b[lane + 64]);
        *(us16*)(base + ((rb * 384 + (lane + 128) * 2) ^ sw)) = f2bf((v2 - m) * inv * ln2_g[lane + 128] + ln2_b[lane + 128]);
    }
    __syncthreads();
    // ---- Phase 1: hid = gelu(xb @ fc1 + fc1_b); wave w covers cols [w*96, w*96+96) ----
    {
        f32x4 acc[2][6] = {};
        int nb = w * 96;
        int swA = (lr & 7) << 4;
        #pragma unroll
        for (int kk = 0; kk < 6; kk++) {
            int k = kk * 32 + g * 8;
            bf16x8 a0 = *(const bf16x8*)((char*)xb + ((lr * 384 + k * 2) ^ swA));
            bf16x8 a1 = *(const bf16x8*)((char*)xb + (((lr + 16) * 384 + k * 2) ^ swA));
            #pragma unroll
            for (int j = 0; j < 6; j++) {
                bf16x8 bv = *(const bf16x8*)(w1T + (size_t)(nb + j * 16 + lr) * CC + k);
                acc[0][j] = __builtin_amdgcn_mfma_f32_16x16x32_bf16(a0, bv, acc[0][j], 0, 0, 0);
                acc[1][j] = __builtin_amdgcn_mfma_f32_16x16x32_bf16(a1, bv, acc[1][j], 0, 0, 0);
            }
        }
        #pragma unroll
        for (int j = 0; j < 6; j++) {
            int n = nb + j * 16 + lr;
            float bias = fc1_b[n];
            #pragma unroll
            for (int i = 0; i < 2; i++) {
                #pragma unroll
                for (int r = 0; r < 4; r++) {
                    int mrow = i * 16 + g * 4 + r;
                    float val = gelu_f(acc[i][j][r] + bias);
                    *(us16*)((char*)hid + ((mrow * 1536 + n * 2) ^ ((mrow & 7) << 4))) = f2bf(val);
                }
            }
        }
    }
    __syncthreads();
    // ---- Phase 2: y = hid @ fc2 + fc2_b + x1 (residual); wave grid 2x4 ----
    {
        int wm = w >> 2, wn = w & 3;
        f32x4 acc[3] = {};
        int row = wm * 16 + lr;
        int sw  = (row & 7) << 4;
        #pragma unroll 4
        for (int kk = 0; kk < 24; kk++) {
            int k = kk * 32 + g * 8;
            bf16x8 a = *(const bf16x8*)((char*)hid + ((row * 1536 + k * 2) ^ sw));
            #pragma unroll
            for (int j = 0; j < 3; j++) {
                bf16x8 bv = *(const bf16x8*)(w2T + (size_t)(wn * 48 + j * 16 + lr) * HIDN + k);
                acc[j] = __builtin_amdgcn_mfma_f32_16x16x32_bf16(a, bv, acc[j], 0, 0, 0);
            }
        }
        #pragma unroll
        for (int j = 0; j < 3; j++) {
            int col = wn * 48 + j * 16 + lr;
            float bias = fc2_b[col];
            #pragma unroll
            for (int r = 0; r < 4; r++) {
                int grow = m0 + wm * 16 + g * 4 + r;
                outp[(size_t)grow * CC + col] = acc[j][r] + bias + x1[(size_t)grow * CC + col];
            }
        }
    }
}

extern "C" void kernel_launch(void* const* d_in, const int* in_sizes, int n_in,
                              void* d_out, int out_size, void* d_ws, size_t ws_size,
                              hipStream_t stream) {
    const float* x      = (const float*)d_in[0];
    const float* ln1_g  = (const float*)d_in[1];
    const float* ln1_b  = (const float*)d_in[2];
    const float* f_w    = (const float*)d_in[3];
    const float* f_b    = (const float*)d_in[4];
    const float* fk0    = (const float*)d_in[5];
    const float* fk1    = (const float*)d_in[6];
    const float* fk2    = (const float*)d_in[7];
    const float* h_w    = (const float*)d_in[8];
    const float* h_b    = (const float*)d_in[9];
    const float* proj_w = (const float*)d_in[10];
    const float* proj_b = (const float*)d_in[11];
    const float* ln2_g  = (const float*)d_in[12];
    const float* ln2_b  = (const float*)d_in[13];
    const float* fc1_w  = (const float*)d_in[14];
    const float* fc1_b  = (const float*)d_in[15];
    const float* fc2_w  = (const float*)d_in[16];
    const float* fc2_b  = (const float*)d_in[17];
    float* outp = (float*)d_out;

    char* ws = (char*)d_ws;
    const size_t S = (size_t)MM * CC * 2;          // 50,331,648 B (one bf16 plane)
    us16* t_buf   = (us16*)(ws);                   // t / xq (reused)
    us16* q_buf   = (us16*)(ws + S);
    us16* ctx_all = (us16*)(ws + 2 * S);
    us16* gates   = (us16*)(ws + 3 * S);
    float* partial = (float*)(ws + 3 * S + 1048576);
    float* hg      = partial + 1024 * CC;
    us16* fwT   = (us16*)(ws + 3 * S + 1048576 + 786432 + 6144);
    us16* hwB   = fwT + 86016;
    us16* projT = hwB + 36864;
    us16* w1T   = projT + 36864;
    us16* w2T   = w1T + 147456;
    // conv ping-pong lives in d_out (dead until proj rewrites it fully)
    us16* ctxA = (us16*)d_out;
    us16* ctxB = (us16*)d_out + (size_t)MM * CC;

    wcvt_kernel<<<1776, 256, 0, stream>>>(f_w, h_w, proj_w, fc1_w, fc2_w,
                                          fwT, hwB, projT, w1T, w2T);

    ln_kernel<<<MM / 4, 256, 0, stream>>>(x, ln1_g, ln1_b, t_buf);

    mgemm_kernel<0><<<8 * 128 * 7, 256, 0, stream>>>(
        t_buf, fwT, f_b, q_buf, ctxA, gates, nullptr, nullptr, nullptr, nullptr, nullptr);

    const int convGrid = (MM * CC) / 256;
    conv_kernel<3, true ><<<convGrid, 256, 0, stream>>>(ctxA, ctxB, ctx_all, gates, fk0, 0);
    conv_kernel<5, false><<<convGrid, 256, 0, stream>>>(ctxB, ctxA, ctx_all, gates, fk1, 1);
    conv_kernel<7, false><<<convGrid, 256, 0, stream>>>(ctxA, ctxB, ctx_all, gates, fk2, 2);

    gmean1_kernel<<<1024, 192, 0, stream>>>(ctxB, partial);
    gmean2_kernel<<<1, 256, 0, stream>>>(partial, h_w, hg);

    mgemm_kernel<1><<<8 * 128 * 3, 256, 0, stream>>>(
        ctx_all, hwB, h_b, t_buf, nullptr, nullptr, q_buf, gates, hg, nullptr, nullptr);

    mgemm_kernel<2><<<8 * 128 * 3, 256, 0, stream>>>(
        t_buf, projT, proj_b, nullptr, nullptr, nullptr, nullptr, nullptr, nullptr, x, outp);

    mlpf_kernel<<<MM / MB, 512, 0, stream>>>(outp, ln2_g, ln2_b,
                                             w1T, fc1_b, w2T, fc2_b, outp);
}

// Round 3
// 1297.272 us; speedup vs baseline: 3.6708x; 2.2465x over previous
//
#include <hip/hip_runtime.h>
#include <hip/hip_bf16.h>

#define BB   8
#define HGT  128
#define WID  128
#define CC   192
#define LLEN (HGT*WID)        // 16384
#define MM   (BB*LLEN)        // 131072
#define NF   388              // 2C + FL + 1
#define HIDN 768

typedef unsigned short us16;
typedef __attribute__((ext_vector_type(8))) short bf16x8;
typedef __attribute__((ext_vector_type(4))) float f32x4;

__device__ __forceinline__ float bf2f(us16 u) {
    return __uint_as_float(((unsigned int)u) << 16);
}
__device__ __forceinline__ us16 f2bf(float f) {
    unsigned int x = __float_as_uint(f);
    x = (x + 0x7fffu + ((x >> 16) & 1u)) >> 16;
    return (us16)x;
}
__device__ __forceinline__ float gelu_f(float x) {
    return 0.5f * x * (1.0f + erff(x * 0.70710678118654752f));
}

// ---------------- Weight convert: fp32 -> bf16, transposed ----------
// GEMM weights -> [N][K]; conv kernels -> [ky*F+kx][C]
__global__ __launch_bounds__(256) void wcvt_kernel(const float* __restrict__ f_w,
        const float* __restrict__ h_w, const float* __restrict__ proj_w,
        const float* __restrict__ fc1_w, const float* __restrict__ fc2_w,
        const float* __restrict__ fk0, const float* __restrict__ fk1,
        const float* __restrict__ fk2,
        us16* __restrict__ fwT, us16* __restrict__ hwB, us16* __restrict__ projT,
        us16* __restrict__ w1T, us16* __restrict__ w2T,
        us16* __restrict__ kw0T, us16* __restrict__ kw1T, us16* __restrict__ kw2T) {
    int i = blockIdx.x * 256 + threadIdx.x;
    if (i < 86016) {                       // fwT: 448 x 192 (pad rows >= 388 = 0)
        int n = i / 192, k = i % 192;
        fwT[i] = (n < NF) ? f2bf(f_w[k * NF + n]) : (us16)0;
        return;
    }
    i -= 86016;
    if (i < 36864) { hwB[i] = f2bf(h_w[i]); return; }       // h_w[o][c] is already [N][K]
    i -= 36864;
    if (i < 36864) { int n = i / 192, k = i % 192; projT[i] = f2bf(proj_w[k * CC + n]); return; }
    i -= 36864;
    if (i < 147456) { int n = i / 192, k = i % 192; w1T[i] = f2bf(fc1_w[k * HIDN + n]); return; }
    i -= 147456;
    if (i < 147456) { int n = i / 768, k = i % 768; w2T[i] = f2bf(fc2_w[k * CC + n]); return; }
    i -= 147456;
    if (i < 1728)  { int kyx = i / 192, c = i % 192; kw0T[i] = f2bf(fk0[c * 9 + kyx]);  return; }
    i -= 1728;
    if (i < 4800)  { int kyx = i / 192, c = i % 192; kw1T[i] = f2bf(fk1[c * 25 + kyx]); return; }
    i -= 4800;
    if (i < 9408)  { int kyx = i / 192, c = i % 192; kw2T[i] = f2bf(fk2[c * 49 + kyx]); return; }
}

// ---------------- LayerNorm: fp32 in -> bf16 out (wave per row) ----------------
__global__ __launch_bounds__(256) void ln_kernel(const float* __restrict__ in,
                                                 const float* __restrict__ g,
                                                 const float* __restrict__ b,
                                                 us16* __restrict__ out) {
    int wid  = threadIdx.x >> 6;
    int lane = threadIdx.x & 63;
    int row  = blockIdx.x * 4 + wid;
    const float* p = in + (size_t)row * CC;
    float v0 = p[lane], v1 = p[lane + 64], v2 = p[lane + 128];
    float s1 = v0 + v1 + v2;
    float s2 = v0*v0 + v1*v1 + v2*v2;
    for (int o = 32; o; o >>= 1) { s1 += __shfl_xor(s1, o); s2 += __shfl_xor(s2, o); }
    float m   = s1 * (1.0f / 192.0f);
    float var = s2 * (1.0f / 192.0f) - m * m;
    float inv = rsqrtf(var + 1e-5f);
    us16* q = out + (size_t)row * CC;
    q[lane]       = f2bf((v0 - m) * inv * g[lane]       + b[lane]);
    q[lane + 64]  = f2bf((v1 - m) * inv * g[lane + 64]  + b[lane + 64]);
    q[lane + 128] = f2bf((v2 - m) * inv * g[lane + 128] + b[lane + 128]);
}

// ---------------- MFMA GEMM: A(bf16 MxK=192) * Bt(bf16 [N][K]) ---------------
template<int MODE>
__global__ __launch_bounds__(256) void mgemm_kernel(const us16* __restrict__ A,
        const us16* __restrict__ Bt, const float* __restrict__ bias,
        us16* __restrict__ out_q, us16* __restrict__ out_ctx, us16* __restrict__ out_g,
        const us16* __restrict__ q_in, const us16* __restrict__ gates_in,
        const float* __restrict__ hg, const float* __restrict__ x_in,
        float* __restrict__ out_f) {
    constexpr int NT = (MODE == 0) ? 7 : 3;
    int id  = blockIdx.x;
    int xcd = id & 7;
    int s   = id >> 3;
    int mt  = xcd * 128 + s / NT;          // all N-tiles of an M-tile on one XCD
    int nt  = s % NT;
    int m0 = mt * 128, n0 = nt * 64;
    int tid = threadIdx.x, lane = tid & 63, w = tid >> 6;
    int wm = w >> 1, wn = w & 1, g = lane >> 4, lr = lane & 15;
    const us16* Ab = A  + (size_t)(m0 + wm * 64 + lr) * CC;
    const us16* Bb = Bt + (size_t)(n0 + wn * 32 + lr) * CC;
    f32x4 acc[4][2] = {};
    #pragma unroll
    for (int kk = 0; kk < 6; kk++) {
        int k = kk * 32 + g * 8;
        bf16x8 a0 = *(const bf16x8*)(Ab + 0 * 16 * CC + k);
        bf16x8 a1 = *(const bf16x8*)(Ab + 1 * 16 * CC + k);
        bf16x8 a2 = *(const bf16x8*)(Ab + 2 * 16 * CC + k);
        bf16x8 a3 = *(const bf16x8*)(Ab + 3 * 16 * CC + k);
        #pragma unroll
        for (int j = 0; j < 2; j++) {
            bf16x8 bv = *(const bf16x8*)(Bb + (size_t)j * 16 * CC + k);
            acc[0][j] = __builtin_amdgcn_mfma_f32_16x16x32_bf16(a0, bv, acc[0][j], 0, 0, 0);
            acc[1][j] = __builtin_amdgcn_mfma_f32_16x16x32_bf16(a1, bv, acc[1][j], 0, 0, 0);
            acc[2][j] = __builtin_amdgcn_mfma_f32_16x16x32_bf16(a2, bv, acc[2][j], 0, 0, 0);
            acc[3][j] = __builtin_amdgcn_mfma_f32_16x16x32_bf16(a3, bv, acc[3][j], 0, 0, 0);
        }
    }
    int orow = m0 + wm * 64;
    #pragma unroll
    for (int i = 0; i < 4; i++) {
        #pragma unroll
        for (int j = 0; j < 2; j++) {
            int ncol = n0 + wn * 32 + j * 16;
            int cc   = ncol + lr;
            #pragma unroll
            for (int r = 0; r < 4; r++) {
                int row = orow + i * 16 + g * 4 + r;
                float v = acc[i][j][r];
                if (MODE == 0) {
                    if (ncol < 192)      out_q[(size_t)row * CC + cc]          = f2bf(v + bias[cc]);
                    else if (ncol < 384) out_ctx[(size_t)row * CC + (cc - 192)] = f2bf(v + bias[cc]);
                    else if (cc < NF)    out_g[(size_t)row * 4 + (cc - 384)]    = f2bf(v + bias[cc]);
                } else if (MODE == 1) {
                    int bidx = row >> 14;
                    float val = v + bias[cc] + bf2f(gates_in[(size_t)row * 4 + 3]) * hg[bidx * CC + cc];
                    val *= bf2f(q_in[(size_t)row * CC + cc]);
                    out_q[(size_t)row * CC + cc] = f2bf(val);
                } else {
                    out_f[(size_t)row * CC + cc] = v + bias[cc] + x_in[(size_t)row * CC + cc];
                }
            }
        }
    }
}

// ---------------- Depthwise conv v2: 4 x-pixels x 8 channels per thread -------
// Vectorized bf16x8 loads + x-sliding-window reuse; weights [kyx][C] bf16 in LDS.
template<int F, bool FIRST>
__global__ __launch_bounds__(256) void convv_kernel(const us16* __restrict__ in,
                            us16* __restrict__ outp,
                            us16* __restrict__ ctx_all,
                            const us16* __restrict__ gates,
                            const us16* __restrict__ kwT, int lvl) {
    constexpr int P  = F / 2;
    constexpr int NW = F + 3;          // row vectors per ky: XT + F - 1, XT = 4
    __shared__ __align__(16) us16 kws[F * F * CC];
    for (int t = threadIdx.x; t < F * F * CC / 8; t += 256)
        ((bf16x8*)kws)[t] = ((const bf16x8*)kwT)[t];
    __syncthreads();
    int idx  = blockIdx.x * 256 + threadIdx.x;   // over (MM/4)*24
    int cg   = idx % 24;
    int rest = idx / 24;                          // b*4096 + y*32 + x4
    int x4 = rest & 31;
    int y0 = (rest >> 5) & 127;
    int b  = rest >> 12;
    int x0 = x4 * 4;
    float acc[4][8] = {};
    const us16* inb = in + (size_t)b * LLEN * CC + cg * 8;
    for (int ky = 0; ky < F; ky++) {
        int yy = y0 + ky - P;
        if (yy < 0 || yy > 127) continue;
        const us16* rp = inb + (size_t)yy * WID * CC;
        float rv[NW][8];
        #pragma unroll
        for (int i = 0; i < NW; i++) {
            int xx = x0 - P + i;
            if (xx >= 0 && xx <= 127) {
                bf16x8 v = *(const bf16x8*)(rp + (size_t)xx * CC);
                #pragma unroll
                for (int j = 0; j < 8; j++) rv[i][j] = bf2f((us16)v[j]);
            } else {
                #pragma unroll
                for (int j = 0; j < 8; j++) rv[i][j] = 0.0f;
            }
        }
        #pragma unroll
        for (int kx = 0; kx < F; kx++) {
            bf16x8 wv = *(const bf16x8*)(kws + (ky * F + kx) * CC + cg * 8);
            float w[8];
            #pragma unroll
            for (int j = 0; j < 8; j++) w[j] = bf2f((us16)wv[j]);
            #pragma unroll
            for (int px = 0; px < 4; px++)
                #pragma unroll
                for (int j = 0; j < 8; j++)
                    acc[px][j] += rv[kx + px][j] * w[j];
        }
    }
    int pix = (b * HGT + y0) * WID + x0;
    size_t obase = (size_t)pix * CC + cg * 8;
    #pragma unroll
    for (int px = 0; px < 4; px++) {
        float gl = bf2f(gates[(size_t)(pix + px) * 4 + lvl]);
        bf16x8 cv;
        if (!FIRST) cv = *(const bf16x8*)(ctx_all + obase + (size_t)px * CC);
        bf16x8 ov, cs;
        #pragma unroll
        for (int j = 0; j < 8; j++) {
            float val = gelu_f(acc[px][j]);
            ov[j] = (short)f2bf(val);
            float contrib = val * gl + (FIRST ? 0.0f : bf2f((us16)cv[j]));
            cs[j] = (short)f2bf(contrib);
        }
        *(bf16x8*)(outp   + obase + (size_t)px * CC) = ov;
        *(bf16x8*)(ctx_all + obase + (size_t)px * CC) = cs;
    }
}

// ---------------- Global mean stage 1 ----------
__global__ __launch_bounds__(192) void gmean1_kernel(const us16* __restrict__ ctx,
                                                     float* __restrict__ partial) {
    int blk = blockIdx.x;           // 0..1023
    int b = blk >> 7, chunk = blk & 127;
    int c = threadIdx.x;
    size_t base = ((size_t)b * LLEN + (size_t)chunk * 128) * CC + c;
    float s = 0.0f;
    for (int p = 0; p < 128; p++) s += bf2f(ctx[base + (size_t)p * CC]);
    partial[(size_t)blk * CC + c] = s;
}

// ---------------- Global mean stage 2 + hg = h_w @ gelu(mean) ------------------
__global__ __launch_bounds__(256) void gmean2_kernel(const float* __restrict__ partial,
                                                     const float* __restrict__ h_w,
                                                     float* __restrict__ hg) {
    __shared__ float ctxg[BB * CC];
    for (int t = threadIdx.x; t < BB * CC; t += 256) {
        int b = t / CC, c = t % CC;
        float s = 0.0f;
        for (int p = 0; p < 128; p++) s += partial[(size_t)(b * 128 + p) * CC + c];
        ctxg[t] = gelu_f(s * (1.0f / 16384.0f));
    }
    __syncthreads();
    for (int t = threadIdx.x; t < BB * CC; t += 256) {
        int b = t / CC, o = t % CC;
        float s = 0.0f;
        for (int c2 = 0; c2 < CC; c2++) s += h_w[o * CC + c2] * ctxg[b * CC + c2];
        hg[t] = s;
    }
}

// ---------------- Fused LN2 + MLP (MFMA), in-place on d_out --------------------
#define MB 32
__global__ __launch_bounds__(512) void mlpf_kernel(const float* __restrict__ x1,
        const float* __restrict__ ln2_g, const float* __restrict__ ln2_b,
        const us16* __restrict__ w1T, const float* __restrict__ fc1_b,
        const us16* __restrict__ w2T, const float* __restrict__ fc2_b,
        float* __restrict__ outp) {
    __shared__ us16 xb[MB * CC];       // 12 KB, swizzled
    __shared__ us16 hid[MB * HIDN];    // 48 KB, swizzled
    int tid = threadIdx.x, lane = tid & 63, w = tid >> 6;
    int g = lane >> 4, lr = lane & 15;
    int m0 = blockIdx.x * MB;
    #pragma unroll
    for (int rr = 0; rr < 4; rr++) {
        int rb = w * 4 + rr;
        const float* p = x1 + (size_t)(m0 + rb) * CC;
        float v0 = p[lane], v1 = p[lane + 64], v2 = p[lane + 128];
        float s1 = v0 + v1 + v2, s2 = v0*v0 + v1*v1 + v2*v2;
        for (int o = 32; o; o >>= 1) { s1 += __shfl_xor(s1, o); s2 += __shfl_xor(s2, o); }
        float m   = s1 * (1.0f / 192.0f);
        float inv = rsqrtf(s2 * (1.0f / 192.0f) - m * m + 1e-5f);
        int sw = (rb & 7) << 4;
        char* base = (char*)xb;
        *(us16*)(base + ((rb * 384 + lane * 2)         ^ sw)) = f2bf((v0 - m) * inv * ln2_g[lane]       + ln2_b[lane]);
        *(us16*)(base + ((rb * 384 + (lane + 64) * 2)  ^ sw)) = f2bf((v1 - m) * inv * ln2_g[lane + 64]  + ln2_b[lane + 64]);
        *(us16*)(base + ((rb * 384 + (lane + 128) * 2) ^ sw)) = f2bf((v2 - m) * inv * ln2_g[lane + 128] + ln2_b[lane + 128]);
    }
    __syncthreads();
    {
        f32x4 acc[2][6] = {};
        int nb = w * 96;
        int swA = (lr & 7) << 4;
        #pragma unroll
        for (int kk = 0; kk < 6; kk++) {
            int k = kk * 32 + g * 8;
            bf16x8 a0 = *(const bf16x8*)((char*)xb + ((lr * 384 + k * 2) ^ swA));
            bf16x8 a1 = *(const bf16x8*)((char*)xb + (((lr + 16) * 384 + k * 2) ^ swA));
            #pragma unroll
            for (int j = 0; j < 6; j++) {
                bf16x8 bv = *(const bf16x8*)(w1T + (size_t)(nb + j * 16 + lr) * CC + k);
                acc[0][j] = __builtin_amdgcn_mfma_f32_16x16x32_bf16(a0, bv, acc[0][j], 0, 0, 0);
                acc[1][j] = __builtin_amdgcn_mfma_f32_16x16x32_bf16(a1, bv, acc[1][j], 0, 0, 0);
            }
        }
        #pragma unroll
        for (int j = 0; j < 6; j++) {
            int n = nb + j * 16 + lr;
            float bias = fc1_b[n];
            #pragma unroll
            for (int i = 0; i < 2; i++) {
                #pragma unroll
                for (int r = 0; r < 4; r++) {
                    int mrow = i * 16 + g * 4 + r;
                    float val = gelu_f(acc[i][j][r] + bias);
                    *(us16*)((char*)hid + ((mrow * 1536 + n * 2) ^ ((mrow & 7) << 4))) = f2bf(val);
                }
            }
        }
    }
    __syncthreads();
    {
        int wm = w >> 2, wn = w & 3;
        f32x4 acc[3] = {};
        int row = wm * 16 + lr;
        int sw  = (row & 7) << 4;
        #pragma unroll 4
        for (int kk = 0; kk < 24; kk++) {
            int k = kk * 32 + g * 8;
            bf16x8 a = *(const bf16x8*)((char*)hid + ((row * 1536 + k * 2) ^ sw));
            #pragma unroll
            for (int j = 0; j < 3; j++) {
                bf16x8 bv = *(const bf16x8*)(w2T + (size_t)(wn * 48 + j * 16 + lr) * HIDN + k);
                acc[j] = __builtin_amdgcn_mfma_f32_16x16x32_bf16(a, bv, acc[j], 0, 0, 0);
            }
        }
        #pragma unroll
        for (int j = 0; j < 3; j++) {
            int col = wn * 48 + j * 16 + lr;
            float bias = fc2_b[col];
            #pragma unroll
            for (int r = 0; r < 4; r++) {
                int grow = m0 + wm * 16 + g * 4 + r;
                outp[(size_t)grow * CC + col] = acc[j][r] + bias + x1[(size_t)grow * CC + col];
            }
        }
    }
}

extern "C" void kernel_launch(void* const* d_in, const int* in_sizes, int n_in,
                              void* d_out, int out_size, void* d_ws, size_t ws_size,
                              hipStream_t stream) {
    const float* x      = (const float*)d_in[0];
    const float* ln1_g  = (const float*)d_in[1];
    const float* ln1_b  = (const float*)d_in[2];
    const float* f_w    = (const float*)d_in[3];
    const float* f_b    = (const float*)d_in[4];
    const float* fk0    = (const float*)d_in[5];
    const float* fk1    = (const float*)d_in[6];
    const float* fk2    = (const float*)d_in[7];
    const float* h_w    = (const float*)d_in[8];
    const float* h_b    = (const float*)d_in[9];
    const float* proj_w = (const float*)d_in[10];
    const float* proj_b = (const float*)d_in[11];
    const float* ln2_g  = (const float*)d_in[12];
    const float* ln2_b  = (const float*)d_in[13];
    const float* fc1_w  = (const float*)d_in[14];
    const float* fc1_b  = (const float*)d_in[15];
    const float* fc2_w  = (const float*)d_in[16];
    const float* fc2_b  = (const float*)d_in[17];
    float* outp = (float*)d_out;

    char* ws = (char*)d_ws;
    const size_t S = (size_t)MM * CC * 2;          // 50,331,648 B (one bf16 plane)
    us16* t_buf   = (us16*)(ws);                   // t / xq (reused)
    us16* q_buf   = (us16*)(ws + S);
    us16* ctx_all = (us16*)(ws + 2 * S);
    us16* gates   = (us16*)(ws + 3 * S);
    float* partial = (float*)(ws + 3 * S + 1048576);
    float* hg      = partial + 1024 * CC;
    us16* fwT   = (us16*)(ws + 3 * S + 1048576 + 786432 + 6144);
    us16* hwB   = fwT + 86016;
    us16* projT = hwB + 36864;
    us16* w1T   = projT + 36864;
    us16* w2T   = w1T + 147456;
    us16* kw0T  = w2T + 147456;
    us16* kw1T  = kw0T + 1728;
    us16* kw2T  = kw1T + 4800;
    // conv ping-pong lives in d_out (dead until proj rewrites it fully)
    us16* ctxA = (us16*)d_out;
    us16* ctxB = (us16*)d_out + (size_t)MM * CC;

    wcvt_kernel<<<1839, 256, 0, stream>>>(f_w, h_w, proj_w, fc1_w, fc2_w,
                                          fk0, fk1, fk2,
                                          fwT, hwB, projT, w1T, w2T, kw0T, kw1T, kw2T);

    ln_kernel<<<MM / 4, 256, 0, stream>>>(x, ln1_g, ln1_b, t_buf);

    mgemm_kernel<0><<<8 * 128 * 7, 256, 0, stream>>>(
        t_buf, fwT, f_b, q_buf, ctxA, gates, nullptr, nullptr, nullptr, nullptr, nullptr);

    const int convGrid = (MM / 4) * 24 / 256;      // 3072
    convv_kernel<3, true ><<<convGrid, 256, 0, stream>>>(ctxA, ctxB, ctx_all, gates, kw0T, 0);
    convv_kernel<5, false><<<convGrid, 256, 0, stream>>>(ctxB, ctxA, ctx_all, gates, kw1T, 1);
    convv_kernel<7, false><<<convGrid, 256, 0, stream>>>(ctxA, ctxB, ctx_all, gates, kw2T, 2);

    gmean1_kernel<<<1024, 192, 0, stream>>>(ctxB, partial);
    gmean2_kernel<<<1, 256, 0, stream>>>(partial, h_w, hg);

    mgemm_kernel<1><<<8 * 128 * 3, 256, 0, stream>>>(
        ctx_all, hwB, h_b, t_buf, nullptr, nullptr, q_buf, gates, hg, nullptr, nullptr);

    mgemm_kernel<2><<<8 * 128 * 3, 256, 0, stream>>>(
        t_buf, projT, proj_b, nullptr, nullptr, nullptr, nullptr, nullptr, nullptr, x, outp);

    mlpf_kernel<<<MM / MB, 512, 0, stream>>>(outp, ln2_g, ln2_b,
                                             w1T, fc1_b, w2T, fc2_b, outp);
}